// Round 5
// baseline (143.323 us; speedup 1.0000x reference)
//
#include <hip/hip_runtime.h>
#include <math.h>

#define Bq 4
#define Nq 128
#define Cq 256
#define HFq 23
#define WFq 30
#define PHq 7
#define PWq 7
#define HIDq 256
#define OUTq 5
#define Fq (Cq*PHq*PWq)      // 12544
#define Mq (Bq*Nq)           // 512
#define HWq (HFq*WFq)        // 690
#define SCALEq (1.0f/32.0f)
#define NEGq (-1e30f)
#define KHq 5                // HF//PH + 2
#define KWq 6                // WF//PW + 2
#define SPLITK 56
#define KCH (Fq/SPLITK)      // 224
#define KSTEPS (KCH/32)      // 7
#define LDP 40               // padded LDS row stride (shorts): 20 words -> 2-way banks
#define TJOBS 704            // 4 imgs * 8 c-tiles * 22 hw-tiles

typedef float f32x4 __attribute__((ext_vector_type(4)));
typedef __bf16 bf16x8 __attribute__((ext_vector_type(8)));

__device__ __forceinline__ unsigned short f2b(float f) {
    unsigned int u = __float_as_uint(f);
    unsigned int r = (u + 0x7FFFu + ((u >> 16) & 1u)) >> 16;
    return (unsigned short)r;
}
__device__ __forceinline__ float b2f(unsigned short s) {
    return __uint_as_float(((unsigned int)s) << 16);
}

union PrepSM {
    float t[32][33];          // transpose staging
    unsigned short s[Fq];     // w1 permute staging (25088 B)
};

// K_prep: bid<704 -> feature transpose (B,C,HF,WF) f32 -> (B,HW,C) bf16
//         bid>=704 -> W1 row j: f32 (c*49+cell) -> bf16 (cell*256+c)
__global__ __launch_bounds__(256) void k_prep(const float* __restrict__ feat,
                                              const float* __restrict__ W1,
                                              unsigned short* __restrict__ ft,
                                              unsigned short* __restrict__ w1p) {
    __shared__ __align__(16) PrepSM sm;
    int tid = threadIdx.x, bid = blockIdx.x;
    if (bid < TJOBS) {
        int bb = bid / 176;
        int rem = bid - bb * 176;
        int cblk = rem / 22;
        int xblk = rem - cblk * 22;
        const float* src = feat + (size_t)bb * Cq * HWq;
        unsigned short* dst = ft + (size_t)bb * HWq * Cq;
        int x0 = xblk * 32, c0 = cblk * 32;
        int tx = tid & 31, ty = tid >> 5;
#pragma unroll
        for (int i = 0; i < 4; ++i) {
            int c = c0 + ty + i * 8, x = x0 + tx;
            if (x < HWq) sm.t[ty + i * 8][tx] = src[(size_t)c * HWq + x];
        }
        __syncthreads();
#pragma unroll
        for (int i = 0; i < 4; ++i) {
            int x = x0 + ty + i * 8, c = c0 + tx;
            if (x < HWq) dst[(size_t)x * Cq + c] = f2b(sm.t[tx][ty + i * 8]);
        }
    } else {
        int j = bid - TJOBS;
        const float4* src = (const float4*)(W1 + (size_t)j * Fq);
        for (int i = tid; i < Fq / 4; i += 256) {
            float4 v = src[i];
            ushort4 o;
            o.x = f2b(v.x); o.y = f2b(v.y); o.z = f2b(v.z); o.w = f2b(v.w);
            ((ushort4*)sm.s)[i] = o;
        }
        __syncthreads();
        uint4* dst = (uint4*)(w1p + (size_t)j * Fq);
        for (int i = tid; i < Fq / 8; i += 256) {
            int base = i * 8;
            int cell = base >> 8;
            int c0 = base & 255;
            unsigned short tmp[8];
#pragma unroll
            for (int u = 0; u < 8; ++u) tmp[u] = sm.s[(c0 + u) * 49 + cell];
            dst[i] = *(const uint4*)tmp;
        }
    }
}

// K_pool: one wave per (proposal, cell-group); lane = 4 channels (bf16 loads).
__global__ __launch_bounds__(256) void k_pool(const unsigned short* __restrict__ ft,
                                              const float* __restrict__ props,
                                              unsigned short* __restrict__ pooled) {
    int wave = threadIdx.x >> 6;
    int lane = threadIdx.x & 63;
    int g = blockIdx.y * 4 + wave;   // 0..7
    int m = blockIdx.x;
    int b = m >> 7;
    const float* pr = props + (size_t)m * 5;
    float b0 = pr[0] * SCALEq, b1v = pr[1] * SCALEq;
    float b2v = pr[2] * SCALEq, b3v = pr[3] * SCALEq;
    int x1 = min(max((int)floorf(b0), 0), WFq - 1);
    int y1 = min(max((int)floorf(b1v), 0), HFq - 1);
    int rw = min(max((int)ceilf(b2v) - x1, 1), WFq);
    int rh = min(max((int)ceilf(b3v) - y1, 1), HFq);
    const unsigned short* ftb = ft + (size_t)b * HWq * Cq + lane * 4;
    unsigned short* pm = pooled + (size_t)m * Fq + lane * 4;

    for (int cell = g; cell < PHq * PWq; cell += 8) {
        int ph = cell / 7;
        int pw = cell - ph * 7;
        int hs = y1 + (ph * rh) / PHq;
        int he = min(y1 + ((ph + 1) * rh + PHq - 1) / PHq, HFq);
        int wss = x1 + (pw * rw) / PWq;
        int wee = min(x1 + ((pw + 1) * rw + PWq - 1) / PWq, WFq);
        f32x4 acc = {NEGq, NEGq, NEGq, NEGq};
#pragma unroll
        for (int kh = 0; kh < KHq; ++kh) {
            if (hs + kh < he) {                      // wave-uniform
                const unsigned short* rowp = ftb + (size_t)((hs + kh) * WFq) * Cq;
#pragma unroll
                for (int kw = 0; kw < KWq; ++kw) {
                    if (wss + kw < wee) {            // wave-uniform
                        ushort4 v = *(const ushort4*)(rowp + (size_t)(wss + kw) * Cq);
                        acc.x = fmaxf(acc.x, b2f(v.x));
                        acc.y = fmaxf(acc.y, b2f(v.y));
                        acc.z = fmaxf(acc.z, b2f(v.z));
                        acc.w = fmaxf(acc.w, b2f(v.w));
                    }
                }
            }
        }
        ushort4 o;
        o.x = f2b(acc.x); o.y = f2b(acc.y); o.z = f2b(acc.z); o.w = f2b(acc.w);
        *(ushort4*)(pm + (size_t)cell * Cq) = o;
    }
}

// K_gemm1: 128x128 tiles, SPLITK=56 (7 K-steps), 2-deep register prefetch +
// LDS double buffer, padded LDS (2-way banks). Partials stored bf16.
__global__ __launch_bounds__(256) void k_gemm1(const unsigned short* __restrict__ pooled,
                                               const unsigned short* __restrict__ w1p,
                                               unsigned short* __restrict__ part) {
    __shared__ __align__(16) unsigned short As[2][128 * LDP];
    __shared__ __align__(16) unsigned short Bs[2][128 * LDP];
    int m0 = blockIdx.x * 128;
    int j0 = blockIdx.y * 128;
    int kz = blockIdx.z;
    int tid = threadIdx.x;
    int r = tid >> 2, sg = tid & 3;
    const uint4* apg  = (const uint4*)(pooled + (size_t)(m0 + r) * Fq + kz * KCH + sg * 8);
    const uint4* apg2 = (const uint4*)(pooled + (size_t)(m0 + r + 64) * Fq + kz * KCH + sg * 8);
    const uint4* bpg  = (const uint4*)(w1p + (size_t)(j0 + r) * Fq + kz * KCH + sg * 8);
    const uint4* bpg2 = (const uint4*)(w1p + (size_t)(j0 + r + 64) * Fq + kz * KCH + sg * 8);

    int lane = tid & 63, wv = tid >> 6;
    int q = lane >> 4, mr = lane & 15;
    f32x4 acc[2][8];
#pragma unroll
    for (int a = 0; a < 2; ++a)
#pragma unroll
        for (int b = 0; b < 8; ++b) acc[a][b] = (f32x4){0.f, 0.f, 0.f, 0.f};

    uint4 rA0[2], rA1[2], rB0[2], rB1[2];
    rA0[0] = apg[0]; rA1[0] = apg2[0]; rB0[0] = bpg[0]; rB1[0] = bpg2[0];
    rA0[1] = apg[4]; rA1[1] = apg2[4]; rB0[1] = bpg[4]; rB1[1] = bpg2[4];

    for (int s = 0; s < KSTEPS; ++s) {
        int p = s & 1;
        *(uint4*)(&As[p][r * LDP + sg * 8])        = rA0[p];
        *(uint4*)(&As[p][(r + 64) * LDP + sg * 8]) = rA1[p];
        *(uint4*)(&Bs[p][r * LDP + sg * 8])        = rB0[p];
        *(uint4*)(&Bs[p][(r + 64) * LDP + sg * 8]) = rB1[p];
        __syncthreads();
        if (s + 2 < KSTEPS) {
            rA0[p] = apg[(s + 2) * 4];
            rA1[p] = apg2[(s + 2) * 4];
            rB0[p] = bpg[(s + 2) * 4];
            rB1[p] = bpg2[(s + 2) * 4];
        }
        const unsigned short* Ab = As[p];
        const unsigned short* Bb = Bs[p];
        bf16x8 af0 = *(const bf16x8*)(Ab + (wv * 32 + mr) * LDP + q * 8);
        bf16x8 af1 = *(const bf16x8*)(Ab + (wv * 32 + 16 + mr) * LDP + q * 8);
#pragma unroll
        for (int jf = 0; jf < 8; ++jf) {
            bf16x8 bf = *(const bf16x8*)(Bb + (jf * 16 + mr) * LDP + q * 8);
            acc[0][jf] = __builtin_amdgcn_mfma_f32_16x16x32_bf16(af0, bf, acc[0][jf], 0, 0, 0);
            acc[1][jf] = __builtin_amdgcn_mfma_f32_16x16x32_bf16(af1, bf, acc[1][jf], 0, 0, 0);
        }
    }
    unsigned short* pbase = part + (size_t)kz * Mq * HIDq;
#pragma unroll
    for (int mf = 0; mf < 2; ++mf) {
        int mb = m0 + wv * 32 + mf * 16 + q * 4;
#pragma unroll
        for (int jf = 0; jf < 8; ++jf) {
            int jj = j0 + jf * 16 + mr;
#pragma unroll
            for (int r2 = 0; r2 < 4; ++r2) {
                pbase[(size_t)(mb + r2) * HIDq + jj] = f2b(acc[mf][jf][r2]);
            }
        }
    }
}

// K_tail: split-K reduce (bf16 partials) + bias + ReLU + GEMM2 + epilogue.
__global__ __launch_bounds__(256) void k_tail(const unsigned short* __restrict__ part,
                                              const float* __restrict__ b1,
                                              const float* __restrict__ W2,
                                              const float* __restrict__ b2,
                                              const float* __restrict__ props,
                                              float* __restrict__ out) {
    __shared__ float red[OUTq][4];
    int m = blockIdx.x, j = threadIdx.x;
    float s = 0.f;
#pragma unroll
    for (int z = 0; z < SPLITK; ++z) s += b2f(part[((size_t)z * Mq + m) * HIDq + j]);
    s += b1[j];
    float hv = fmaxf(s, 0.f);
    float p[OUTq];
#pragma unroll
    for (int o = 0; o < OUTq; ++o) p[o] = hv * W2[(size_t)o * HIDq + j];
    int lane = j & 63, wid = j >> 6;
#pragma unroll
    for (int o = 0; o < OUTq; ++o) {
        float v = p[o];
        v += __shfl_xor(v, 1);
        v += __shfl_xor(v, 2);
        v += __shfl_xor(v, 4);
        v += __shfl_xor(v, 8);
        v += __shfl_xor(v, 16);
        v += __shfl_xor(v, 32);
        if (lane == 0) red[o][wid] = v;
    }
    __syncthreads();
    if (j < OUTq) {
        float sv = red[j][0] + red[j][1] + red[j][2] + red[j][3] + b2[j];
        float pv = props[(size_t)m * 5 + j];
        float rr;
        if (j < 4) rr = pv + sv;
        else rr = 1.f / (1.f + expf(-(pv + sv)));
        out[(size_t)m * 5 + j] = rr;
    }
}

extern "C" void kernel_launch(void* const* d_in, const int* in_sizes, int n_in,
                              void* d_out, int out_size, void* d_ws, size_t ws_size,
                              hipStream_t stream) {
    const float* feat  = (const float*)d_in[0];   // (4,256,23,30)
    const float* props = (const float*)d_in[1];   // (4,128,5)
    const float* W1    = (const float*)d_in[2];   // (256,12544)
    const float* b1    = (const float*)d_in[3];   // (256,)
    const float* W2    = (const float*)d_in[4];   // (5,256)
    const float* b2    = (const float*)d_in[5];   // (5,)
    float* out = (float*)d_out;

    char* ws = (char*)d_ws;
    unsigned short* ft     = (unsigned short*)(ws);             // 1,413,120 B
    unsigned short* w1p    = (unsigned short*)(ws + 1413120);   // 6,422,528 B
    unsigned short* pooled = (unsigned short*)(ws + 7835648);   // 12,845,056 B
    unsigned short* part   = (unsigned short*)(ws + 20680704);  // 14,680,064 B -> 35,360,768 total

    k_prep<<<TJOBS + HIDq, 256, 0, stream>>>(feat, W1, ft, w1p);
    k_pool<<<dim3(Mq, 2), 256, 0, stream>>>(ft, props, pooled);
    k_gemm1<<<dim3(4, 2, SPLITK), 256, 0, stream>>>(pooled, w1p, part);
    k_tail<<<Mq, 256, 0, stream>>>(part, b1, W2, b2, props, out);
}

// Round 6
// 134.777 us; speedup vs baseline: 1.0634x; 1.0634x over previous
//
#include <hip/hip_runtime.h>
#include <math.h>

#define Bq 4
#define Nq 128
#define Cq 256
#define HFq 23
#define WFq 30
#define PHq 7
#define PWq 7
#define HIDq 256
#define OUTq 5
#define Fq (Cq*PHq*PWq)      // 12544
#define Mq (Bq*Nq)           // 512
#define HWq (HFq*WFq)        // 690
#define SCALEq (1.0f/32.0f)
#define NEGq (-1e30f)
#define KHq 5                // HF//PH + 2
#define KWq 6                // WF//PW + 2
#define SPLITK 56
#define KCH (Fq/SPLITK)      // 224
#define KSTEPS (KCH/32)      // 7
#define TJOBS 704            // 4 imgs * 8 c-tiles * 22 hw-tiles

typedef float f32x4 __attribute__((ext_vector_type(4)));
typedef __bf16 bf16x8 __attribute__((ext_vector_type(8)));

__device__ __forceinline__ unsigned short f2b(float f) {
    unsigned int u = __float_as_uint(f);
    unsigned int r = (u + 0x7FFFu + ((u >> 16) & 1u)) >> 16;
    return (unsigned short)r;
}
__device__ __forceinline__ float b2f(unsigned short s) {
    return __uint_as_float(((unsigned int)s) << 16);
}

union PrepSM {
    float t[32][33];          // transpose staging
    unsigned short s[Fq];     // w1 permute staging (25088 B)
};

// K_prep: bid<704 -> feature transpose (B,C,HF,WF) f32 -> (B,HW,C) bf16
//         bid>=704 -> W1 row j: f32 (c*49+cell) -> bf16 (cell*256+c)
__global__ __launch_bounds__(256) void k_prep(const float* __restrict__ feat,
                                              const float* __restrict__ W1,
                                              unsigned short* __restrict__ ft,
                                              unsigned short* __restrict__ w1p) {
    __shared__ __align__(16) PrepSM sm;
    int tid = threadIdx.x, bid = blockIdx.x;
    if (bid < TJOBS) {
        int bb = bid / 176;
        int rem = bid - bb * 176;
        int cblk = rem / 22;
        int xblk = rem - cblk * 22;
        const float* src = feat + (size_t)bb * Cq * HWq;
        unsigned short* dst = ft + (size_t)bb * HWq * Cq;
        int x0 = xblk * 32, c0 = cblk * 32;
        int tx = tid & 31, ty = tid >> 5;
#pragma unroll
        for (int i = 0; i < 4; ++i) {
            int c = c0 + ty + i * 8, x = x0 + tx;
            if (x < HWq) sm.t[ty + i * 8][tx] = src[(size_t)c * HWq + x];
        }
        __syncthreads();
#pragma unroll
        for (int i = 0; i < 4; ++i) {
            int x = x0 + ty + i * 8, c = c0 + tx;
            if (x < HWq) dst[(size_t)x * Cq + c] = f2b(sm.t[tx][ty + i * 8]);
        }
    } else {
        int j = bid - TJOBS;
        const float4* src = (const float4*)(W1 + (size_t)j * Fq);
        for (int i = tid; i < Fq / 4; i += 256) {
            float4 v = src[i];
            ushort4 o;
            o.x = f2b(v.x); o.y = f2b(v.y); o.z = f2b(v.z); o.w = f2b(v.w);
            ((ushort4*)sm.s)[i] = o;
        }
        __syncthreads();
        uint4* dst = (uint4*)(w1p + (size_t)j * Fq);
        for (int i = tid; i < Fq / 8; i += 256) {
            int base = i * 8;
            int cell = base >> 8;
            int c0 = base & 255;
            unsigned short tmp[8];
#pragma unroll
            for (int u = 0; u < 8; ++u) tmp[u] = sm.s[(c0 + u) * 49 + cell];
            dst[i] = *(const uint4*)tmp;
        }
    }
}

// K_pool: one wave per (proposal, cell-group); lane = 4 channels (bf16 loads).
__global__ __launch_bounds__(256) void k_pool(const unsigned short* __restrict__ ft,
                                              const float* __restrict__ props,
                                              unsigned short* __restrict__ pooled) {
    int wave = threadIdx.x >> 6;
    int lane = threadIdx.x & 63;
    int g = blockIdx.y * 4 + wave;   // 0..7
    int m = blockIdx.x;
    int b = m >> 7;
    const float* pr = props + (size_t)m * 5;
    float b0 = pr[0] * SCALEq, b1v = pr[1] * SCALEq;
    float b2v = pr[2] * SCALEq, b3v = pr[3] * SCALEq;
    int x1 = min(max((int)floorf(b0), 0), WFq - 1);
    int y1 = min(max((int)floorf(b1v), 0), HFq - 1);
    int rw = min(max((int)ceilf(b2v) - x1, 1), WFq);
    int rh = min(max((int)ceilf(b3v) - y1, 1), HFq);
    const unsigned short* ftb = ft + (size_t)b * HWq * Cq + lane * 4;
    unsigned short* pm = pooled + (size_t)m * Fq + lane * 4;

    for (int cell = g; cell < PHq * PWq; cell += 8) {
        int ph = cell / 7;
        int pw = cell - ph * 7;
        int hs = y1 + (ph * rh) / PHq;
        int he = min(y1 + ((ph + 1) * rh + PHq - 1) / PHq, HFq);
        int wss = x1 + (pw * rw) / PWq;
        int wee = min(x1 + ((pw + 1) * rw + PWq - 1) / PWq, WFq);
        f32x4 acc = {NEGq, NEGq, NEGq, NEGq};
#pragma unroll
        for (int kh = 0; kh < KHq; ++kh) {
            if (hs + kh < he) {                      // wave-uniform
                const unsigned short* rowp = ftb + (size_t)((hs + kh) * WFq) * Cq;
#pragma unroll
                for (int kw = 0; kw < KWq; ++kw) {
                    if (wss + kw < wee) {            // wave-uniform
                        ushort4 v = *(const ushort4*)(rowp + (size_t)(wss + kw) * Cq);
                        acc.x = fmaxf(acc.x, b2f(v.x));
                        acc.y = fmaxf(acc.y, b2f(v.y));
                        acc.z = fmaxf(acc.z, b2f(v.z));
                        acc.w = fmaxf(acc.w, b2f(v.w));
                    }
                }
            }
        }
        ushort4 o;
        o.x = f2b(acc.x); o.y = f2b(acc.y); o.z = f2b(acc.z); o.w = f2b(acc.w);
        *(ushort4*)(pm + (size_t)cell * Cq) = o;
    }
}

// K_gemm1: zero-LDS, barrier-free MFMA GEMM. Wave = 64x64 tile x K-chunk.
// A/B fragments loaded directly from global as per-lane uint4 (L2/LLC-hit),
// 2-deep register prefetch. Grid: (8 m-tiles, 56 kz). Wave w -> j0 = w*64.
__global__ __launch_bounds__(256) void k_gemm1(const unsigned short* __restrict__ pooled,
                                               const unsigned short* __restrict__ w1p,
                                               float* __restrict__ part) {
    int tid = threadIdx.x;
    int wv = tid >> 6, lane = tid & 63;
    int q = lane >> 4, mr = lane & 15;
    int m0 = blockIdx.x * 64;
    int j0 = wv * 64;
    int kz = blockIdx.y;

    // per-lane fragment pointers: frag g covers rows (g*16 .. g*16+15), lane row mr,
    // k offset q*8 shorts; step stride = 32 shorts = 4 uint4.
    const uint4* ap[4];
    const uint4* bp[4];
#pragma unroll
    for (int g = 0; g < 4; ++g) {
        ap[g] = (const uint4*)(pooled + (size_t)(m0 + g * 16 + mr) * Fq + kz * KCH + q * 8);
        bp[g] = (const uint4*)(w1p   + (size_t)(j0 + g * 16 + mr) * Fq + kz * KCH + q * 8);
    }

    f32x4 acc[4][4];
#pragma unroll
    for (int a = 0; a < 4; ++a)
#pragma unroll
        for (int b = 0; b < 4; ++b) acc[a][b] = (f32x4){0.f, 0.f, 0.f, 0.f};

    uint4 abuf[3][4], bbuf[3][4];
#pragma unroll
    for (int g = 0; g < 4; ++g) {
        abuf[0][g] = ap[g][0]; bbuf[0][g] = bp[g][0];
        abuf[1][g] = ap[g][4]; bbuf[1][g] = bp[g][4];
    }
#pragma unroll
    for (int s = 0; s < KSTEPS; ++s) {
        int cur = s % 3;
        int nxt = (s + 2) % 3;
        if (s + 2 < KSTEPS) {
#pragma unroll
            for (int g = 0; g < 4; ++g) {
                abuf[nxt][g] = ap[g][(s + 2) * 4];
                bbuf[nxt][g] = bp[g][(s + 2) * 4];
            }
        }
#pragma unroll
        for (int mg = 0; mg < 4; ++mg) {
            bf16x8 af = *(const bf16x8*)&abuf[cur][mg];
#pragma unroll
            for (int jg = 0; jg < 4; ++jg) {
                bf16x8 bf = *(const bf16x8*)&bbuf[cur][jg];
                acc[mg][jg] = __builtin_amdgcn_mfma_f32_16x16x32_bf16(af, bf, acc[mg][jg], 0, 0, 0);
            }
        }
    }
    float* pbase = part + (size_t)kz * Mq * HIDq;
#pragma unroll
    for (int mg = 0; mg < 4; ++mg) {
        int mb = m0 + mg * 16 + q * 4;
#pragma unroll
        for (int jg = 0; jg < 4; ++jg) {
            int jj = j0 + jg * 16 + mr;
#pragma unroll
            for (int r2 = 0; r2 < 4; ++r2) {
                pbase[(size_t)(mb + r2) * HIDq + jj] = acc[mg][jg][r2];
            }
        }
    }
}

// K_tail: split-K reduce (f32) + bias + ReLU + GEMM2 + epilogue. Block per proposal.
__global__ __launch_bounds__(256) void k_tail(const float* __restrict__ part,
                                              const float* __restrict__ b1,
                                              const float* __restrict__ W2,
                                              const float* __restrict__ b2,
                                              const float* __restrict__ props,
                                              float* __restrict__ out) {
    __shared__ float red[OUTq][4];
    int m = blockIdx.x, j = threadIdx.x;
    float s = 0.f;
#pragma unroll
    for (int z = 0; z < SPLITK; ++z) s += part[((size_t)z * Mq + m) * HIDq + j];
    s += b1[j];
    float hv = fmaxf(s, 0.f);
    float p[OUTq];
#pragma unroll
    for (int o = 0; o < OUTq; ++o) p[o] = hv * W2[(size_t)o * HIDq + j];
    int lane = j & 63, wid = j >> 6;
#pragma unroll
    for (int o = 0; o < OUTq; ++o) {
        float v = p[o];
        v += __shfl_xor(v, 1);
        v += __shfl_xor(v, 2);
        v += __shfl_xor(v, 4);
        v += __shfl_xor(v, 8);
        v += __shfl_xor(v, 16);
        v += __shfl_xor(v, 32);
        if (lane == 0) red[o][wid] = v;
    }
    __syncthreads();
    if (j < OUTq) {
        float sv = red[j][0] + red[j][1] + red[j][2] + red[j][3] + b2[j];
        float pv = props[(size_t)m * 5 + j];
        float rr;
        if (j < 4) rr = pv + sv;
        else rr = 1.f / (1.f + expf(-(pv + sv)));
        out[(size_t)m * 5 + j] = rr;
    }
}

extern "C" void kernel_launch(void* const* d_in, const int* in_sizes, int n_in,
                              void* d_out, int out_size, void* d_ws, size_t ws_size,
                              hipStream_t stream) {
    const float* feat  = (const float*)d_in[0];   // (4,256,23,30)
    const float* props = (const float*)d_in[1];   // (4,128,5)
    const float* W1    = (const float*)d_in[2];   // (256,12544)
    const float* b1    = (const float*)d_in[3];   // (256,)
    const float* W2    = (const float*)d_in[4];   // (5,256)
    const float* b2    = (const float*)d_in[5];   // (5,)
    float* out = (float*)d_out;

    char* ws = (char*)d_ws;
    unsigned short* ft     = (unsigned short*)(ws);             // 1,413,120 B
    unsigned short* w1p    = (unsigned short*)(ws + 1413120);   // 6,422,528 B
    unsigned short* pooled = (unsigned short*)(ws + 7835648);   // 12,845,056 B
    float* part            = (float*)(ws + 20680704);           // 29,360,128 B -> 50,040,832 total

    k_prep<<<TJOBS + HIDq, 256, 0, stream>>>(feat, W1, ft, w1p);
    k_pool<<<dim3(Mq, 2), 256, 0, stream>>>(ft, props, pooled);
    k_gemm1<<<dim3(8, SPLITK), 256, 0, stream>>>(pooled, w1p, part);
    k_tail<<<Mq, 256, 0, stream>>>(part, b1, W2, b2, props, out);
}